// Round 11
// baseline (96.881 us; speedup 1.0000x reference)
//
#include <hip/hip_runtime.h>

// ---------------------------------------------------------------------------
// BetterGooLayer R11: chain-latency attack on the fused sim.
// R10 post-mortem: 74us with VALU 17%/DS ~20%/mem ~30% — sum-of-pipes,
// latency-bound (two serial 16-step walks + f64 scan per wave).
// R11: (1) rewalk replaced by linear correction dir_j = dir0_j - [A^j s]x
// (outputs affine in start state; acc = fma(k,dir,f) stays reference-exact);
// (2) chunk scan all-f32 (error ~1e-5 << threshold); (3) u-form state update
// (3-op chain). One barrier, one h-read, wave-local LDS transposes as R10.
// ---------------------------------------------------------------------------

#define NS    8192
#define BB    4
#define MM    64
#define DD    8
#define NF    8
#define FL    256
#define DAMP  0.9998f
#define SEG   2048

#define REC_OFF  0
#define DISP_OFF (BB*MM*NS)                 // 2097152
#define HF_OFF   (DISP_OFF + BB*MM*DD*NS)   // 18874368

#define SW(i) ((i) + ((i) >> 5))

struct Mat { float a, b, c, d; };
__device__ __forceinline__ Mat matmul(Mat x, Mat y) {
    Mat r;
    r.a = fmaf(x.a, y.a, x.b * y.c);
    r.b = fmaf(x.a, y.b, x.b * y.d);
    r.c = fmaf(x.c, y.a, x.d * y.c);
    r.d = fmaf(x.c, y.b, x.d * y.d);
    return r;
}

// ---------------- threefry2x32 (JAX, partitionable counters) ----------------
__device__ __forceinline__ unsigned rotl32(unsigned x, int r) {
    return (x << r) | (x >> (32 - r));
}
__device__ float jax_noise(unsigned idx) {
    const unsigned ks0 = 0u;
    const unsigned ks1 = 123u;
    const unsigned ks2 = 0x1BD11BDAu ^ 0u ^ 123u;
    unsigned x0 = 0u  + ks0;
    unsigned x1 = idx + ks1;
#define TF_RND(r) { x0 += x1; x1 = rotl32(x1, r); x1 ^= x0; }
    TF_RND(13) TF_RND(15) TF_RND(26) TF_RND(6)
    x0 += ks1; x1 += ks2 + 1u;
    TF_RND(17) TF_RND(29) TF_RND(16) TF_RND(24)
    x0 += ks2; x1 += ks0 + 2u;
    TF_RND(13) TF_RND(15) TF_RND(26) TF_RND(6)
    x0 += ks0; x1 += ks1 + 3u;
    TF_RND(17) TF_RND(29) TF_RND(16) TF_RND(24)
    x0 += ks1; x1 += ks2 + 4u;
    TF_RND(13) TF_RND(15) TF_RND(26) TF_RND(6)
    x0 += ks2; x1 += ks0 + 5u;
#undef TF_RND
    unsigned bits = x0 ^ x1;
    float u = __uint_as_float((bits >> 9) | 0x3f800000u) - 1.0f;  // [0,1)
    return fmaxf(-0.01f, u * 0.02f - 0.01f);
}

// ---------------- fused sim: block = (bm,d) chain, 512 threads --------------
__global__ __launch_bounds__(512, 6) void sim_fused(
    const float* __restrict__ forces, const float* __restrict__ hm,
    const float* __restrict__ home,   const float* __restrict__ cs,
    const float* __restrict__ masses, const float* __restrict__ tens,
    const float* __restrict__ mics,   float* __restrict__ out,
    float* __restrict__ part)
{
    __shared__ __align__(16) float sbuf[8][1280];   // 40 KB wave-local
    __shared__ float2 qcL[64];

    int bmd  = blockIdx.x;          // bm*8 + d
    int bm   = bmd >> 3;
    int d    = bmd & 7;
    int tid  = threadIdx.x;
    int wl   = tid >> 6;
    int lane = tid & 63;
    int sub  = lane & 7;
    int m    = bm & (MM - 1);

    float ms  = masses[m];
    float k   = tens[m * DD + d] / ms;
    float csm = cs[m];
    float hd  = home[d];
    float mm_ = ms * mics[m * DD + d];

    float* sb = sbuf[wl];
    int wp = (lane >> 2) * 20 + (lane & 3) * 4;
    size_t gbase = (size_t)bmd * NS + wl * 1024;

    // issue all 8 coalesced loads up front
    float4 t0 = *(const float4*)(forces + gbase +   0 + 4 * lane);
    float4 t1 = *(const float4*)(forces + gbase + 256 + 4 * lane);
    float4 t2 = *(const float4*)(forces + gbase + 512 + 4 * lane);
    float4 t3 = *(const float4*)(forces + gbase + 768 + 4 * lane);
    float4 u0 = *(const float4*)(hm + gbase +   0 + 4 * lane);
    float4 u1 = *(const float4*)(hm + gbase + 256 + 4 * lane);
    float4 u2 = *(const float4*)(hm + gbase + 512 + 4 * lane);
    float4 u3 = *(const float4*)(hm + gbase + 768 + 4 * lane);

    // transpose forces -> registers
    *(float4*)(sb + wp +   0) = t0;
    *(float4*)(sb + wp + 320) = t1;
    *(float4*)(sb + wp + 640) = t2;
    *(float4*)(sb + wp + 960) = t3;
    float4 fq[4];
#pragma unroll
    for (int q = 0; q < 4; ++q)
        fq[q] = *(const float4*)(sb + lane * 20 + 4 * q);
    // transpose hm -> LDS (resident through walk1)
    *(float4*)(sb + wp +   0) = u0;
    *(float4*)(sb + wp + 320) = u1;
    *(float4*)(sb + wp + 640) = u2;
    *(float4*)(sb + wp + 960) = u3;

    const float* fr = (const float*)fq;

    // walk1 from zero state (u-form, short chain), capture dir0[16]
    float dir0[16];
    float pos = 0.f, vel = 0.f;
#pragma unroll
    for (int q = 0; q < 4; ++q) {
        float4 hv = *(const float4*)(sb + lane * 20 + 4 * q);
        float hh[4] = {hv.x, hv.y, hv.z, hv.w};
#pragma unroll
        for (int i = 0; i < 4; ++i) {
            float ht = fmaf(hh[i], csm, hd);          // off-chain
            float u  = fmaf(k, ht, fr[q * 4 + i]);    // off-chain
            dir0[q * 4 + i] = ht - pos;               // off-chain
            float w  = fmaf(-k, pos, u);              // == acc0 (u-form)
            vel = (vel + w) * DAMP;
            pos += vel;
        }
    }
    float Wx = pos, Wy = vel;

    Mat A   = {1.f - DAMP * k, DAMP, -DAMP * k, DAMP};
    Mat A2  = matmul(A, A);
    Mat A4  = matmul(A2, A2);
    Mat A8  = matmul(A4, A4);
    Mat M0  = matmul(A8, A8);      // A^16
    Mat M1  = matmul(M0, M0);      // A^32
    Mat M2  = matmul(M1, M1);      // A^64
    Mat P = {1.f, 0.f, 0.f, 1.f};  // (A^16)^sub
    if (sub & 1) P = matmul(P, M0);
    if (sub & 2) P = matmul(P, M1);
    if (sub & 4) P = matmul(P, M2);

    // octet Kogge-Stone (f32) within 8-lane groups
    {
        float ox, oy;
        ox = __shfl_up(Wx, 1, 64); oy = __shfl_up(Wy, 1, 64);
        if (sub >= 1) { float nx = Wx + fmaf(M0.a, ox, M0.b * oy);
                        float ny = Wy + fmaf(M0.c, ox, M0.d * oy);
                        Wx = nx; Wy = ny; }
        ox = __shfl_up(Wx, 2, 64); oy = __shfl_up(Wy, 2, 64);
        if (sub >= 2) { float nx = Wx + fmaf(M1.a, ox, M1.b * oy);
                        float ny = Wy + fmaf(M1.c, ox, M1.d * oy);
                        Wx = nx; Wy = ny; }
        ox = __shfl_up(Wx, 4, 64); oy = __shfl_up(Wy, 4, 64);
        if (sub >= 4) { float nx = Wx + fmaf(M2.a, ox, M2.b * oy);
                        float ny = Wy + fmaf(M2.c, ox, M2.d * oy);
                        Wx = nx; Wy = ny; }
    }
    float Ex = __shfl_up(Wx, 1, 64);
    float Ey = __shfl_up(Wy, 1, 64);
    if (sub == 0) { Ex = 0.f; Ey = 0.f; }
    if (sub == 7) qcL[tid >> 3] = make_float2(Wx, Wy);

    __syncthreads();   // the ONLY block barrier

    // f32 chunk scan over 64 chunks, redundantly in every wave (lane = chunk)
    float s0x, s0y;
    {
        Mat B = matmul(M2, M2);     // A^128
        float2 qv = qcL[lane];
        float sx = qv.x, sy = qv.y;
        Mat Kr = B;
#pragma unroll
        for (int r = 0; r < 6; ++r) {
            float ox = __shfl_up(sx, 1 << r, 64);
            float oy = __shfl_up(sy, 1 << r, 64);
            if (lane >= (1 << r)) {
                float nx = fmaf(Kr.a, ox, fmaf(Kr.b, oy, sx));
                float ny = fmaf(Kr.c, ox, fmaf(Kr.d, oy, sy));
                sx = nx; sy = ny;
            }
            if (r < 5) Kr = matmul(Kr, Kr);
        }
        int srcl = (tid >> 3) - 1;
        float px = __shfl(sx, srcl & 63, 64);
        float py = __shfl(sy, srcl & 63, 64);
        if (srcl < 0) { px = 0.f; py = 0.f; }
        s0x = px; s0y = py;
    }

    // window-start state, then linear correction pass (no rewalk)
    float ex = fmaf(P.a, s0x, fmaf(P.b, s0y, Ex));
    float ey = fmaf(P.c, s0x, fmaf(P.d, s0y, Ey));

    float rv[16];
#pragma unroll
    for (int q = 0; q < 4; ++q) {
        float dv[4];
#pragma unroll
        for (int i = 0; i < 4; ++i) {
            int j = q * 4 + i;
            float dir = dir0[j] - ex;                 // dir = dir0 - [A^j s]x
            float acc = fmaf(k, dir, fr[j]);          // reference-exact form
            dv[i] = dir;
            rv[j] = mm_ * acc;
            float nx = fmaf(A.a, ex, A.b * ey);       // e <- A e
            float ny = fmaf(A.c, ex, A.d * ey);
            ex = nx; ey = ny;
        }
        *(float4*)(sb + lane * 20 + 4 * q) =
            make_float4(dv[0], dv[1], dv[2], dv[3]);  // overwrites h slots
    }
    // flush disp coalesced
#pragma unroll
    for (int i = 0; i < 4; ++i) {
        float4 v = *(const float4*)(sb + wp + i * 320);
        *(float4*)(out + DISP_OFF + gbase + i * 256 + 4 * lane) = v;
    }
    // stage rv rows, flush partial rec coalesced
#pragma unroll
    for (int q = 0; q < 4; ++q)
        *(float4*)(sb + lane * 20 + 4 * q) =
            make_float4(rv[q * 4], rv[q * 4 + 1], rv[q * 4 + 2], rv[q * 4 + 3]);
#pragma unroll
    for (int i = 0; i < 4; ++i) {
        float4 v = *(const float4*)(sb + wp + i * 320);
        *(float4*)(part + gbase + i * 256 + 4 * lane) = v;
    }
}

// ---------------- HF kernel: 8-partial sum + noise + FIR + rec/hf write -----
// Grid 1024 = 256 (b,m) x 4 segments of 2048.
__global__ __launch_bounds__(256) void hf_kernel(
    const float* __restrict__ part,
    const float* __restrict__ filters, const float* __restrict__ tfm,
    const float* __restrict__ bias,    const float* __restrict__ hf_gain,
    float* __restrict__ out)
{
    __shared__ float up[SW(FL + SEG) + 8];
    __shared__ float recL[SEG];
    __shared__ float gtap[FL];
    int bm  = blockIdx.x >> 2;
    int seg = blockIdx.x & 3;
    int b = bm >> 6;
    int m = bm & 63;
    int tx = threadIdx.x;
    int T0 = seg * SEG;

    float gs = 0.f;
#pragma unroll
    for (int f = 0; f < NF; ++f) {
        float mix = 0.f;
#pragma unroll
        for (int dd = 0; dd < DD; ++dd)
            mix = fmaf(bias[m * DD + dd], tfm[(m * DD + dd) * NF + f], mix);
        gs = fmaf(mix, filters[(b * NF + f) * FL + tx], gs);
    }
    gtap[tx] = gs;

    const float* pb = part + (size_t)(bm * DD) * NS;
    for (int j = tx; j < FL + SEG; j += 256) {
        int t = T0 - FL + j;
        float v = 0.f, r = 0.f;
        if (t >= 0) {
            r = ((pb[t] + pb[t + NS]) + (pb[t + 2 * NS] + pb[t + 3 * NS]))
              + ((pb[t + 4 * NS] + pb[t + 5 * NS])
               + (pb[t + 6 * NS] + pb[t + 7 * NS]));
            v = fabsf(r) * jax_noise((unsigned)(bm * NS + t));
        }
        up[SW(j)] = v;
        if (j >= FL) recL[j - FL] = r;
    }
    __syncthreads();

    float gain = hf_gain[0];
    int t0 = tx * 8;
    float acc[8] = {0, 0, 0, 0, 0, 0, 0, 0};
    float w[8];
#pragma unroll
    for (int j = 0; j < 8; ++j) w[j] = up[SW(t0 + 1 + j)];
#pragma unroll 8
    for (int s = 255; s >= 1; --s) {
        float gv = gtap[s];
#pragma unroll
        for (int j = 0; j < 8; ++j) acc[j] = fmaf(gv, w[j], acc[j]);
#pragma unroll
        for (int j = 0; j < 7; ++j) w[j] = w[j + 1];
        w[7] = up[SW(FL + t0 + 8 - s)];
    }
    float g0 = gtap[0];
#pragma unroll
    for (int j = 0; j < 8; ++j) acc[j] = fmaf(g0, w[j], acc[j]);
    float4 r0 = *(const float4*)(&recL[t0]);
    float4 r1 = *(const float4*)(&recL[t0 + 4]);
    float4 o0 = make_float4(fmaf(gain, acc[0], r0.x), fmaf(gain, acc[1], r0.y),
                            fmaf(gain, acc[2], r0.z), fmaf(gain, acc[3], r0.w));
    float4 o1 = make_float4(fmaf(gain, acc[4], r1.x), fmaf(gain, acc[5], r1.y),
                            fmaf(gain, acc[6], r1.z), fmaf(gain, acc[7], r1.w));
    size_t rowoff = (size_t)bm * NS + T0 + t0;
    *(float4*)(out + HF_OFF + rowoff)     = o0;
    *(float4*)(out + HF_OFF + rowoff + 4) = o1;
    *(float4*)(out + REC_OFF + rowoff)     = r0;
    *(float4*)(out + REC_OFF + rowoff + 4) = r1;
}

extern "C" void kernel_launch(void* const* d_in, const int* in_sizes, int n_in,
                              void* d_out, int out_size, void* d_ws, size_t ws_size,
                              hipStream_t stream)
{
    const float* forces  = (const float*)d_in[0];
    const float* hm      = (const float*)d_in[1];
    const float* filters = (const float*)d_in[2];
    const float* home    = (const float*)d_in[3];
    const float* cs      = (const float*)d_in[4];
    const float* masses  = (const float*)d_in[5];
    const float* tens    = (const float*)d_in[6];
    const float* mics    = (const float*)d_in[7];
    const float* tfm     = (const float*)d_in[8];
    const float* bias    = (const float*)d_in[9];
    const float* gain    = (const float*)d_in[10];
    float* out = (float*)d_out;

    float* part = (float*)d_ws;    // 2048 rows x 8192 floats = 64 MiB

    sim_fused<<<BB * MM * DD, 512, 0, stream>>>(
        forces, hm, home, cs, masses, tens, mics, out, part);
    hf_kernel<<<BB * MM * 4, 256, 0, stream>>>(
        part, filters, tfm, bias, gain, out);
}